// Round 3
// baseline (11576.300 us; speedup 1.0000x reference)
//
#include <hip/hip_runtime.h>

// RWKV block (B=8,T=2048,C=2048,F=8192) for MI355X/gfx950.
// fp32 logical precision via split-bf16 MFMA (hi/lo, 3 products, ~2^-16 rel err).
// Workspace requirement: 4 * B*T*C * 4B = 536,870,912 bytes.

#define DEVI __device__ __forceinline__

constexpr int BB = 8, TT = 2048, CC = 2048, FF = 8192;
constexpr long long BTC = (long long)BB * TT * CC;

typedef __attribute__((ext_vector_type(8))) __bf16 bf16x8;
typedef __attribute__((ext_vector_type(4))) float f32x4;

DEVI unsigned short f2b(float f) {            // f32 -> bf16 bits, round-nearest-even
    unsigned int u = __float_as_uint(f);
    return (unsigned short)((u + 0x7FFFu + ((u >> 16) & 1u)) >> 16);
}
DEVI float b2f(unsigned short h) { return __uint_as_float(((unsigned int)h) << 16); }
DEVI unsigned pk(unsigned short a, unsigned short b) {
    return (unsigned)a | ((unsigned)b << 16);
}

// Raw barriers: keep prefetched global loads in flight across the barrier
// (__syncthreads would emit s_waitcnt vmcnt(0) and drain them — m97's ~20% stall).
// sched_barrier(0) sandwich pins DS ops to their side of the barrier (rule #18).
DEVI void barrier_before_read() {   // after ds_writes: drain LDS only
    __builtin_amdgcn_sched_barrier(0);
    asm volatile("s_waitcnt lgkmcnt(0)" ::: "memory");
    __builtin_amdgcn_s_barrier();
    __builtin_amdgcn_sched_barrier(0);
}
DEVI void barrier_after_read() {    // after MFMA: own ds_reads already drained via reg deps
    __builtin_amdgcn_sched_barrier(0);
    __builtin_amdgcn_s_barrier();
    __builtin_amdgcn_sched_barrier(0);
}

// ---------------------------------------------------------------------------
// LayerNorm over last dim (C=2048). 1 block (256 thr) per row. Also emits the
// t==T-1 row into lastOut (the xa[:, -1] / xf[:, -1] outputs).
// ---------------------------------------------------------------------------
__global__ __launch_bounds__(256)
void ln_kernel(const float* __restrict__ x, const float* __restrict__ g,
               const float* __restrict__ b, float* __restrict__ y,
               float* __restrict__ lastOut)
{
    const int row = blockIdx.x;
    const int tid = threadIdx.x;
    const float* xr = x + (size_t)row * CC;
    const int c0 = tid << 2, c1 = c0 + 1024;
    const float4 a = *(const float4*)&xr[c0];
    const float4 c = *(const float4*)&xr[c1];
    float s1 = a.x + a.y + a.z + a.w + c.x + c.y + c.z + c.w;
    float s2 = a.x*a.x + a.y*a.y + a.z*a.z + a.w*a.w
             + c.x*c.x + c.y*c.y + c.z*c.z + c.w*c.w;
#pragma unroll
    for (int o = 32; o > 0; o >>= 1) { s1 += __shfl_xor(s1, o); s2 += __shfl_xor(s2, o); }
    __shared__ float r1[4], r2[4];
    const int wid = tid >> 6;
    if ((tid & 63) == 0) { r1[wid] = s1; r2[wid] = s2; }
    __syncthreads();
    s1 = r1[0] + r1[1] + r1[2] + r1[3];
    s2 = r2[0] + r2[1] + r2[2] + r2[3];
    const float mean = s1 * (1.f / CC);
    const float var  = s2 * (1.f / CC) - mean * mean;
    const float rstd = rsqrtf(var + 1e-5f);
    const float4 g0 = *(const float4*)&g[c0], g1 = *(const float4*)&g[c1];
    const float4 b0 = *(const float4*)&b[c0], b1 = *(const float4*)&b[c1];
    float4 y0, y1;
    y0.x = (a.x - mean) * rstd * g0.x + b0.x;
    y0.y = (a.y - mean) * rstd * g0.y + b0.y;
    y0.z = (a.z - mean) * rstd * g0.z + b0.z;
    y0.w = (a.w - mean) * rstd * g0.w + b0.w;
    y1.x = (c.x - mean) * rstd * g1.x + b1.x;
    y1.y = (c.y - mean) * rstd * g1.y + b1.y;
    y1.z = (c.z - mean) * rstd * g1.z + b1.z;
    y1.w = (c.w - mean) * rstd * g1.w + b1.w;
    *(float4*)&y[(size_t)row * CC + c0] = y0;
    *(float4*)&y[(size_t)row * CC + c1] = y1;
    if ((row & (TT - 1)) == TT - 1) {
        const int bi = row >> 11;                       // row / T
        *(float4*)&lastOut[(size_t)bi * CC + c0] = y0;
        *(float4*)&lastOut[(size_t)bi * CC + c1] = y1;
    }
}

// ---------------------------------------------------------------------------
// WKV scan. One lane per (b,c) channel; 256 blocks x 64 threads. Prefetch
// depth 32 (96 outstanding dwords/lane) to amortize HBM latency. Fuses
// sigmoid(r)*y, overwriting the r buffer (same element, same lane: safe).
// ---------------------------------------------------------------------------
__global__ __launch_bounds__(64, 1)
void wkv_kernel(const float* __restrict__ k, const float* __restrict__ v,
                const float* r, const float* __restrict__ td,
                const float* __restrict__ tf, const float* __restrict__ st,
                float* sry, float* __restrict__ stOut)
{
    const int gid = blockIdx.x * 64 + threadIdx.x;      // 0 .. B*C-1
    const int c = gid & (CC - 1);
    const float w = -__expf(td[c]);
    const float u = tf[c];
    float aa = st[gid * 3 + 0], bb = st[gid * 3 + 1], pp = st[gid * 3 + 2];
    size_t off = (size_t)(gid >> 11) * TT * CC + c;
    constexpr int PF = 32;
    for (int tb = 0; tb < TT; tb += PF) {
        float ck[PF], cv[PF], cr[PF];
#pragma unroll
        for (int i = 0; i < PF; ++i) {
            ck[i] = k[off + (size_t)i * CC];
            cv[i] = v[off + (size_t)i * CC];
            cr[i] = r[off + (size_t)i * CC];
        }
#pragma unroll
        for (int i = 0; i < PF; ++i) {
            const float kt = ck[i], vt = cv[i];
            const float ww = u + kt;
            const float p  = fmaxf(pp, ww);
            const float e1 = __expf(pp - p), e2 = __expf(ww - p);
            const float yv = __fdividef(e1 * aa + e2 * vt, e1 * bb + e2);
            const float sr = __fdividef(1.f, 1.f + __expf(-cr[i]));
            sry[off + (size_t)i * CC] = sr * yv;
            const float ww2 = pp + w;
            const float p2  = fmaxf(ww2, kt);
            const float e1b = __expf(ww2 - p2), e2b = __expf(kt - p2);
            aa = e1b * aa + e2b * vt;
            bb = e1b * bb + e2b;
            pp = p2;
        }
        off += (size_t)PF * CC;
    }
    stOut[gid * 3 + 0] = aa;
    stOut[gid * 3 + 1] = bb;
    stOut[gid * 3 + 2] = pp;
}

// ---------------------------------------------------------------------------
// Split-bf16 GEMM:  out[m,n] = epi( sum_k Amix[m,k] * W[n,k] )
// A fp32; optional fused token-shift mix: Amix = prev + mix*(cur - prev),
// prev = row m-1 (or shift[b] at t==0). A and W split to hi/lo bf16 during
// staging; 3 MFMA products (hh, hl, lh) per fragment pair.
// Tile 128x128, BK=64, 256 thr (4 waves 2x2), LDS 64KB -> 2 blocks/CU.
// T14: next K-tile's A/W/prev float4s all prefetched in regs across raw
// barriers (prev rides the same pipeline — keeps staging phase load-free).
// T1: XCD-swizzled tile id (all grids are %8==0).
// T5: s_setprio around the MFMA phase (2 async blocks/CU -> role diversity).
// EPI: 0 none | 1 +X1 | 2 relu^2 | 3 X1 + sigmoid(acc)*X2
// ---------------------------------------------------------------------------
template<int EPI, bool MIX>
__global__ __launch_bounds__(256, 2)
void gemm_kernel(const float* __restrict__ A, const float* __restrict__ W,
                 const float* __restrict__ mixv, const float* __restrict__ shiftv,
                 const float* __restrict__ X1, const float* __restrict__ X2,
                 float* __restrict__ out, int N, int K, int aRowOff, int oRowOff)
{
    __shared__ unsigned short Ah[128 * 64], Al[128 * 64];
    __shared__ unsigned short Bh[128 * 64], Bl[128 * 64];

    const int tid = threadIdx.x;
    const int nwg = gridDim.x;                              // %8 == 0 for all launches
    const int wg  = (blockIdx.x & 7) * (nwg >> 3) + (blockIdx.x >> 3);  // XCD swizzle
    const int nTiles = N >> 7;
    const int mt = wg / nTiles, nt = wg - mt * nTiles;
    const int m0 = mt << 7, n0 = nt << 7;

    const int trow = tid >> 3;              // 0..31 (staging row)
    const int tcol = (tid & 7) << 3;        // 0..56 (8-float column group)

    const int lane = tid & 63, wid = tid >> 6;
    const int wm = (wid >> 1) << 6, wn = (wid & 1) << 6;
    const int lr = lane & 15, ls = lane >> 4;

    f32x4 acc[4][4];
#pragma unroll
    for (int i = 0; i < 4; ++i)
#pragma unroll
        for (int j = 0; j < 4; ++j)
#pragma unroll
            for (int q = 0; q < 4; ++q) acc[i][j][q] = 0.f;

    const float* aBase = A + (size_t)(aRowOff + m0 + trow) * K + tcol;
    const float* wBase = W + (size_t)(n0 + trow) * K + tcol;

    // Per-r4 prev-row base (token-shift): row-1 of A, or shift row at t==0.
    const float* pBase[4];
    if (MIX) {
#pragma unroll
        for (int r4 = 0; r4 < 4; ++r4) {
            const int gm = aRowOff + m0 + trow + (r4 << 5);
            pBase[r4] = ((gm & (TT - 1)) == 0)
                ? (shiftv + (size_t)(gm >> 11) * CC + tcol)
                : (A + (size_t)(gm - 1) * K + tcol);
        }
    }

    float4 aP[8], wP[8], pP[8];             // prefetch regs: [r4*2 + half]
    auto issue = [&](int kt) {
#pragma unroll
        for (int r4 = 0; r4 < 4; ++r4) {
            const float* ap = aBase + (size_t)(r4 << 5) * K + kt;
            const float* wp = wBase + (size_t)(r4 << 5) * K + kt;
            aP[r4 * 2 + 0] = *(const float4*)(ap);
            aP[r4 * 2 + 1] = *(const float4*)(ap + 4);
            wP[r4 * 2 + 0] = *(const float4*)(wp);
            wP[r4 * 2 + 1] = *(const float4*)(wp + 4);
            if (MIX) {
                const float* pp_ = pBase[r4] + kt;
                pP[r4 * 2 + 0] = *(const float4*)(pp_);
                pP[r4 * 2 + 1] = *(const float4*)(pp_ + 4);
            }
        }
    };
    issue(0);

    for (int kt = 0; kt < K; kt += 64) {
        float mxv[8];
        if (MIX) {
            const float4 mA = *(const float4*)&mixv[kt + tcol];
            const float4 mB = *(const float4*)&mixv[kt + tcol + 4];
            mxv[0] = mA.x; mxv[1] = mA.y; mxv[2] = mA.z; mxv[3] = mA.w;
            mxv[4] = mB.x; mxv[5] = mB.y; mxv[6] = mB.z; mxv[7] = mB.w;
        }
        // ---- convert prefetched regs, ds_write_b128 into swizzled LDS ----
#pragma unroll
        for (int r4 = 0; r4 < 4; ++r4) {
            const int row = trow + (r4 << 5);
            float av[8] = { aP[r4*2].x,   aP[r4*2].y,   aP[r4*2].z,   aP[r4*2].w,
                            aP[r4*2+1].x, aP[r4*2+1].y, aP[r4*2+1].z, aP[r4*2+1].w };
            if (MIX) {
                const float pr[8] = { pP[r4*2].x,   pP[r4*2].y,   pP[r4*2].z,   pP[r4*2].w,
                                      pP[r4*2+1].x, pP[r4*2+1].y, pP[r4*2+1].z, pP[r4*2+1].w };
#pragma unroll
                for (int e = 0; e < 8; ++e) av[e] = pr[e] + mxv[e] * (av[e] - pr[e]);
            }
            unsigned short h[8], l[8];
#pragma unroll
            for (int e = 0; e < 8; ++e) { h[e] = f2b(av[e]); l[e] = f2b(av[e] - b2f(h[e])); }
            const unsigned off = ((unsigned)row << 6) + (unsigned)tcol;
            const unsigned swz = off ^ (((unsigned)(row & 7)) << 3);
            *(uint4*)&Ah[swz] = make_uint4(pk(h[0],h[1]), pk(h[2],h[3]), pk(h[4],h[5]), pk(h[6],h[7]));
            *(uint4*)&Al[swz] = make_uint4(pk(l[0],l[1]), pk(l[2],l[3]), pk(l[4],l[5]), pk(l[6],l[7]));

            const float wv[8] = { wP[r4*2].x,   wP[r4*2].y,   wP[r4*2].z,   wP[r4*2].w,
                                  wP[r4*2+1].x, wP[r4*2+1].y, wP[r4*2+1].z, wP[r4*2+1].w };
#pragma unroll
            for (int e = 0; e < 8; ++e) { h[e] = f2b(wv[e]); l[e] = f2b(wv[e] - b2f(h[e])); }
            *(uint4*)&Bh[swz] = make_uint4(pk(h[0],h[1]), pk(h[2],h[3]), pk(h[4],h[5]), pk(h[6],h[7]));
            *(uint4*)&Bl[swz] = make_uint4(pk(l[0],l[1]), pk(l[2],l[3]), pk(l[4],l[5]), pk(l[6],l[7]));
        }
        if (kt + 64 < K) issue(kt + 64);    // prefetch stays in flight across barrier
        barrier_before_read();
        // ---- MFMA: acc += Ah*Bh + Ah*Bl + Al*Bh (grouped: dep distance 4) ----
#pragma unroll
        for (int kk = 0; kk < 2; ++kk) {
            bf16x8 ah[4], al[4], bh[4], bl[4];
#pragma unroll
            for (int i = 0; i < 4; ++i) {
                const int ar = wm + (i << 4) + lr;
                const unsigned ao = (((unsigned)ar << 6) + (kk << 5) + (ls << 3))
                                    ^ (((unsigned)(ar & 7)) << 3);
                ah[i] = *(const bf16x8*)&Ah[ao];
                al[i] = *(const bf16x8*)&Al[ao];
                const int br = wn + (i << 4) + lr;
                const unsigned bo = (((unsigned)br << 6) + (kk << 5) + (ls << 3))
                                    ^ (((unsigned)(br & 7)) << 3);
                bh[i] = *(const bf16x8*)&Bh[bo];
                bl[i] = *(const bf16x8*)&Bl[bo];
            }
            __builtin_amdgcn_s_setprio(1);
#pragma unroll
            for (int i = 0; i < 4; ++i) {
#pragma unroll
                for (int j = 0; j < 4; ++j)
                    acc[i][j] = __builtin_amdgcn_mfma_f32_16x16x32_bf16(ah[i], bh[j], acc[i][j], 0, 0, 0);
#pragma unroll
                for (int j = 0; j < 4; ++j)
                    acc[i][j] = __builtin_amdgcn_mfma_f32_16x16x32_bf16(ah[i], bl[j], acc[i][j], 0, 0, 0);
#pragma unroll
                for (int j = 0; j < 4; ++j)
                    acc[i][j] = __builtin_amdgcn_mfma_f32_16x16x32_bf16(al[i], bh[j], acc[i][j], 0, 0, 0);
            }
            __builtin_amdgcn_s_setprio(0);
        }
        barrier_after_read();
    }
    // ---- epilogue (C/D layout: col = lane&15, row = (lane>>4)*4 + reg) ----
#pragma unroll
    for (int i = 0; i < 4; ++i) {
        const int gr0 = oRowOff + m0 + wm + (i << 4) + (ls << 2);
#pragma unroll
        for (int j = 0; j < 4; ++j) {
            const int gc = n0 + wn + (j << 4) + lr;
#pragma unroll
            for (int q = 0; q < 4; ++q) {
                const size_t o = (size_t)(gr0 + q) * N + gc;
                float val = acc[i][j][q];
                if constexpr (EPI == 1) {
                    val += X1[o];
                } else if constexpr (EPI == 2) {
                    val = fmaxf(val, 0.f); val *= val;
                } else if constexpr (EPI == 3) {
                    const float s = __fdividef(1.f, 1.f + __expf(-val));
                    val = X1[o] + s * X2[o];
                }
                out[o] = val;
            }
        }
    }
}

// ---------------------------------------------------------------------------
extern "C" void kernel_launch(void* const* d_in, const int* in_sizes, int n_in,
                              void* d_out, int out_size, void* d_ws, size_t ws_size,
                              hipStream_t stream)
{
    (void)in_sizes; (void)n_in; (void)out_size; (void)ws_size;
    const float* x   = (const float*)d_in[0];
    const float* sha = (const float*)d_in[1];
    const float* shf = (const float*)d_in[2];
    const float* wst = (const float*)d_in[3];
    const float* l1g = (const float*)d_in[4];
    const float* l1b = (const float*)d_in[5];
    const float* l2g = (const float*)d_in[6];
    const float* l2b = (const float*)d_in[7];
    const float* tmk = (const float*)d_in[8];
    const float* tmv = (const float*)d_in[9];
    const float* tmr = (const float*)d_in[10];
    const float* td  = (const float*)d_in[11];
    const float* tf  = (const float*)d_in[12];
    const float* Wk  = (const float*)d_in[13];
    const float* Wv  = (const float*)d_in[14];
    const float* Wr  = (const float*)d_in[15];
    const float* Wo  = (const float*)d_in[16];
    const float* fmk = (const float*)d_in[17];
    const float* fmr = (const float*)d_in[18];
    const float* Wkf = (const float*)d_in[19];
    const float* Wvf = (const float*)d_in[20];
    const float* Wrf = (const float*)d_in[21];

    float* xa = (float*)d_ws;           // [B*T, C]  xa; later reused as kf chunk
    float* bK = xa + BTC;               // k; later x1
    float* bV = bK + BTC;               // v; later xf
    float* bR = bV + BTC;               // r -> sr*y; later kv

    float* o_x  = (float*)d_out;                 // x out        [B,T,C]
    float* o_xa = o_x + BTC;                     // xa[:, -1]    [B,C]
    float* o_xf = o_xa + (size_t)BB * CC;        // xf[:, -1]    [B,C]
    float* o_st = o_xf + (size_t)BB * CC;        // new_wkv      [B,C,3]

    const int M = BB * TT;                       // 16384
    const int gCC = (M / 128) * (CC / 128);      // 2048 blocks
    dim3 blk(256);

    // ---- attention (time-mix) ----
    ln_kernel<<<M, blk, 0, stream>>>(x, l1g, l1b, xa, o_xa);
    gemm_kernel<0, true><<<gCC, blk, 0, stream>>>(xa, Wk, tmk, sha, nullptr, nullptr, bK, CC, CC, 0, 0);
    gemm_kernel<0, true><<<gCC, blk, 0, stream>>>(xa, Wv, tmv, sha, nullptr, nullptr, bV, CC, CC, 0, 0);
    gemm_kernel<0, true><<<gCC, blk, 0, stream>>>(xa, Wr, tmr, sha, nullptr, nullptr, bR, CC, CC, 0, 0);
    wkv_kernel<<<BB * CC / 64, dim3(64), 0, stream>>>(bK, bV, bR, td, tf, wst, bR, o_st);
    gemm_kernel<1, false><<<gCC, blk, 0, stream>>>(bR, Wo, nullptr, nullptr, x, nullptr, bK, CC, CC, 0, 0);

    // ---- FFN (channel-mix) ----
    ln_kernel<<<M, blk, 0, stream>>>(bK, l2g, l2b, bV, o_xf);
    for (int ch = 0; ch < 4; ++ch) {             // 4096-row chunks
        gemm_kernel<2, true><<<(4096 / 128) * (FF / 128), blk, 0, stream>>>(
            bV, Wkf, fmk, shf, nullptr, nullptr, xa, FF, CC, ch * 4096, 0);
        gemm_kernel<0, false><<<(4096 / 128) * (CC / 128), blk, 0, stream>>>(
            xa, Wvf, nullptr, nullptr, nullptr, nullptr, bR, CC, FF, 0, ch * 4096);
    }
    gemm_kernel<3, true><<<gCC, blk, 0, stream>>>(bV, Wrf, fmr, shf, bK, bR, o_x, CC, CC, 0, 0);
}

// Round 5
// 10028.659 us; speedup vs baseline: 1.1543x; 1.1543x over previous
//
#include <hip/hip_runtime.h>

// RWKV block (B=8,T=2048,C=2048,F=8192) for MI355X/gfx950.
// fp32 logical precision via split-bf16 MFMA (hi/lo, 3 products, ~2^-16 rel err).
// Workspace requirement: 4 * B*T*C * 4B = 536,870,912 bytes.
//
// R3 counters: GEMMs HBM-bound (2.27GB @1.85TB/s = dur). Fixes this round:
//  - nt-outer/mt-inner tile order: W panels stay L2/L3-hot (was: W re-fetched
//    from HBM per mt-row, ~1.3GB/dispatch extra), A becomes the L3-resident
//    re-read stream (134MB < 256MB L3).
//  - k/v/r fused into one dispatch, which-innermost: A-slice shared via L2.
//  - split conversion via native (__bf16) casts (v_cvt_pk_bf16_f32) instead
//    of manual integer RNE: ~3x fewer conversion VALU ops.

#define DEVI __device__ __forceinline__

constexpr int BB = 8, TT = 2048, CC = 2048, FF = 8192;
constexpr long long BTC = (long long)BB * TT * CC;

typedef __attribute__((ext_vector_type(8))) __bf16 bf16x8;
typedef __attribute__((ext_vector_type(4))) float f32x4;

// Raw barriers: keep prefetched global loads in flight across the barrier
// (__syncthreads would emit s_waitcnt vmcnt(0) and drain them — m97's ~20% stall).
// sched_barrier(0) sandwich pins DS ops to their side of the barrier (rule #18).
DEVI void barrier_before_read() {   // after ds_writes: drain LDS only
    __builtin_amdgcn_sched_barrier(0);
    asm volatile("s_waitcnt lgkmcnt(0)" ::: "memory");
    __builtin_amdgcn_s_barrier();
    __builtin_amdgcn_sched_barrier(0);
}
DEVI void barrier_after_read() {    // after MFMA: own ds_reads already drained via reg deps
    __builtin_amdgcn_sched_barrier(0);
    __builtin_amdgcn_s_barrier();
    __builtin_amdgcn_sched_barrier(0);
}

// ---------------------------------------------------------------------------
// LayerNorm over last dim (C=2048). 1 block (256 thr) per row. Also emits the
// t==T-1 row into lastOut (the xa[:, -1] / xf[:, -1] outputs).
// ---------------------------------------------------------------------------
__global__ __launch_bounds__(256)
void ln_kernel(const float* __restrict__ x, const float* __restrict__ g,
               const float* __restrict__ b, float* __restrict__ y,
               float* __restrict__ lastOut)
{
    const int row = blockIdx.x;
    const int tid = threadIdx.x;
    const float* xr = x + (size_t)row * CC;
    const int c0 = tid << 2, c1 = c0 + 1024;
    const float4 a = *(const float4*)&xr[c0];
    const float4 c = *(const float4*)&xr[c1];
    float s1 = a.x + a.y + a.z + a.w + c.x + c.y + c.z + c.w;
    float s2 = a.x*a.x + a.y*a.y + a.z*a.z + a.w*a.w
             + c.x*c.x + c.y*c.y + c.z*c.z + c.w*c.w;
#pragma unroll
    for (int o = 32; o > 0; o >>= 1) { s1 += __shfl_xor(s1, o); s2 += __shfl_xor(s2, o); }
    __shared__ float r1[4], r2[4];
    const int wid = tid >> 6;
    if ((tid & 63) == 0) { r1[wid] = s1; r2[wid] = s2; }
    __syncthreads();
    s1 = r1[0] + r1[1] + r1[2] + r1[3];
    s2 = r2[0] + r2[1] + r2[2] + r2[3];
    const float mean = s1 * (1.f / CC);
    const float var  = s2 * (1.f / CC) - mean * mean;
    const float rstd = rsqrtf(var + 1e-5f);
    const float4 g0 = *(const float4*)&g[c0], g1 = *(const float4*)&g[c1];
    const float4 b0 = *(const float4*)&b[c0], b1 = *(const float4*)&b[c1];
    float4 y0, y1;
    y0.x = (a.x - mean) * rstd * g0.x + b0.x;
    y0.y = (a.y - mean) * rstd * g0.y + b0.y;
    y0.z = (a.z - mean) * rstd * g0.z + b0.z;
    y0.w = (a.w - mean) * rstd * g0.w + b0.w;
    y1.x = (c.x - mean) * rstd * g1.x + b1.x;
    y1.y = (c.y - mean) * rstd * g1.y + b1.y;
    y1.z = (c.z - mean) * rstd * g1.z + b1.z;
    y1.w = (c.w - mean) * rstd * g1.w + b1.w;
    *(float4*)&y[(size_t)row * CC + c0] = y0;
    *(float4*)&y[(size_t)row * CC + c1] = y1;
    if ((row & (TT - 1)) == TT - 1) {
        const int bi = row >> 11;                       // row / T
        *(float4*)&lastOut[(size_t)bi * CC + c0] = y0;
        *(float4*)&lastOut[(size_t)bi * CC + c1] = y1;
    }
}

// ---------------------------------------------------------------------------
// WKV scan. One lane per (b,c) channel; 256 blocks x 64 threads. Prefetch
// depth 32 (96 outstanding dwords/lane) to amortize HBM latency. Fuses
// sigmoid(r)*y, overwriting the r buffer (same element, same lane: safe).
// ---------------------------------------------------------------------------
__global__ __launch_bounds__(64, 1)
void wkv_kernel(const float* __restrict__ k, const float* __restrict__ v,
                const float* r, const float* __restrict__ td,
                const float* __restrict__ tf, const float* __restrict__ st,
                float* sry, float* __restrict__ stOut)
{
    const int gid = blockIdx.x * 64 + threadIdx.x;      // 0 .. B*C-1
    const int c = gid & (CC - 1);
    const float w = -__expf(td[c]);
    const float u = tf[c];
    float aa = st[gid * 3 + 0], bb = st[gid * 3 + 1], pp = st[gid * 3 + 2];
    size_t off = (size_t)(gid >> 11) * TT * CC + c;
    constexpr int PF = 32;
    for (int tb = 0; tb < TT; tb += PF) {
        float ck[PF], cv[PF], cr[PF];
#pragma unroll
        for (int i = 0; i < PF; ++i) {
            ck[i] = k[off + (size_t)i * CC];
            cv[i] = v[off + (size_t)i * CC];
            cr[i] = r[off + (size_t)i * CC];
        }
#pragma unroll
        for (int i = 0; i < PF; ++i) {
            const float kt = ck[i], vt = cv[i];
            const float ww = u + kt;
            const float p  = fmaxf(pp, ww);
            const float e1 = __expf(pp - p), e2 = __expf(ww - p);
            const float yv = __fdividef(e1 * aa + e2 * vt, e1 * bb + e2);
            const float sr = __fdividef(1.f, 1.f + __expf(-cr[i]));
            sry[off + (size_t)i * CC] = sr * yv;
            const float ww2 = pp + w;
            const float p2  = fmaxf(ww2, kt);
            const float e1b = __expf(ww2 - p2), e2b = __expf(kt - p2);
            aa = e1b * aa + e2b * vt;
            bb = e1b * bb + e2b;
            pp = p2;
        }
        off += (size_t)PF * CC;
    }
    stOut[gid * 3 + 0] = aa;
    stOut[gid * 3 + 1] = bb;
    stOut[gid * 3 + 2] = pp;
}

// ---------------------------------------------------------------------------
// Split-bf16 GEMM:  out[m,n] = epi( sum_k Amix[m,k] * W[n,k] )
// A fp32; optional fused token-shift mix: Amix = prev + mix*(cur - prev),
// prev = row m-1 (or shift[b] at t==0). A and W split to hi/lo bf16 during
// staging; 3 MFMA products (hh, hl, lh) per fragment pair.
// Tile 128x128, BK=64, 256 thr (4 waves 2x2), LDS 64KB -> 2 blocks/CU.
// NMAT: 1 or 3 weight matrices sharing the same A (which = innermost grid dim
//       -> the 3 blocks of a triple co-reside on one XCD and share A via L2).
// Tile order: nt OUTER, mt INNER (column panels): per-XCD W working set ~2MB
//       (L2-fit); A panel is the re-read stream and stays L3-resident.
// T14: next K-tile's A/W/prev float4s prefetched in regs across raw barriers.
// T1: XCD swizzle (all grids %8==0). T5: setprio around MFMA.
// EPI: 0 none | 1 +X1 | 2 relu^2 | 3 X1 + sigmoid(acc)*X2
// ---------------------------------------------------------------------------
template<int EPI, bool MIX, int NMAT>
__global__ __launch_bounds__(256, 2)
void gemm_kernel(const float* __restrict__ A,
                 const float* __restrict__ W0, const float* __restrict__ W1,
                 const float* __restrict__ W2,
                 const float* __restrict__ mix0, const float* __restrict__ mix1,
                 const float* __restrict__ mix2,
                 const float* __restrict__ shiftv,
                 const float* __restrict__ X1, const float* __restrict__ X2,
                 float* __restrict__ out0, float* __restrict__ out1,
                 float* __restrict__ out2,
                 int N, int K, int aRowOff, int oRowOff)
{
    __shared__ __align__(16) unsigned short Ah[128 * 64], Al[128 * 64];
    __shared__ __align__(16) unsigned short Bh[128 * 64], Bl[128 * 64];

    const int tid = threadIdx.x;
    const int nwg = gridDim.x;                              // %8 == 0 for all launches
    const int wg  = (blockIdx.x & 7) * (nwg >> 3) + (blockIdx.x >> 3);  // XCD swizzle
    const int NT = N >> 7;
    const int MT = nwg / (NT * NMAT);
    const int which = (NMAT == 1) ? 0 : (wg % NMAT);        // innermost: A-share
    const int t2    = (NMAT == 1) ? wg : (wg / NMAT);
    const int mt = t2 % MT;                                 // mt INNER
    const int nt = t2 / MT;                                 // nt OUTER
    const int m0 = mt << 7, n0 = nt << 7;

    const float* Wm  = (NMAT > 1 && which == 2) ? W2 : ((NMAT > 1 && which == 1) ? W1 : W0);
    const float* mxp = (NMAT > 1 && which == 2) ? mix2 : ((NMAT > 1 && which == 1) ? mix1 : mix0);
    float*       out = (NMAT > 1 && which == 2) ? out2 : ((NMAT > 1 && which == 1) ? out1 : out0);

    const int trow = tid >> 3;              // 0..31 (staging row)
    const int tcol = (tid & 7) << 3;        // 0..56 (8-float column group)

    const int lane = tid & 63, wid = tid >> 6;
    const int wm = (wid >> 1) << 6, wn = (wid & 1) << 6;
    const int lr = lane & 15, ls = lane >> 4;

    f32x4 acc[4][4];
#pragma unroll
    for (int i = 0; i < 4; ++i)
#pragma unroll
        for (int j = 0; j < 4; ++j)
#pragma unroll
            for (int q = 0; q < 4; ++q) acc[i][j][q] = 0.f;

    const float* aBase = A + (size_t)(aRowOff + m0 + trow) * K + tcol;
    const float* wBase = Wm + (size_t)(n0 + trow) * K + tcol;

    // Per-r4 prev-row base (token-shift): row-1 of A, or shift row at t==0.
    const float* pBase[4];
    if (MIX) {
#pragma unroll
        for (int r4 = 0; r4 < 4; ++r4) {
            const int gm = aRowOff + m0 + trow + (r4 << 5);
            pBase[r4] = ((gm & (TT - 1)) == 0)
                ? (shiftv + (size_t)(gm >> 11) * CC + tcol)
                : (A + (size_t)(gm - 1) * K + tcol);
        }
    }

    float4 aP[8], wP[8], pP[8];             // prefetch regs: [r4*2 + half]
    auto issue = [&](int kt) {
#pragma unroll
        for (int r4 = 0; r4 < 4; ++r4) {
            const float* ap = aBase + (size_t)(r4 << 5) * K + kt;
            const float* wp = wBase + (size_t)(r4 << 5) * K + kt;
            aP[r4 * 2 + 0] = *(const float4*)(ap);
            aP[r4 * 2 + 1] = *(const float4*)(ap + 4);
            wP[r4 * 2 + 0] = *(const float4*)(wp);
            wP[r4 * 2 + 1] = *(const float4*)(wp + 4);
            if (MIX) {
                const float* pp_ = pBase[r4] + kt;
                pP[r4 * 2 + 0] = *(const float4*)(pp_);
                pP[r4 * 2 + 1] = *(const float4*)(pp_ + 4);
            }
        }
    };
    issue(0);

    for (int kt = 0; kt < K; kt += 64) {
        float mxv[8];
        if (MIX) {
            const float4 mA = *(const float4*)&mxp[kt + tcol];
            const float4 mB = *(const float4*)&mxp[kt + tcol + 4];
            mxv[0] = mA.x; mxv[1] = mA.y; mxv[2] = mA.z; mxv[3] = mA.w;
            mxv[4] = mB.x; mxv[5] = mB.y; mxv[6] = mB.z; mxv[7] = mB.w;
        }
        // ---- convert prefetched regs (v_cvt_pk_bf16_f32 via casts), ds_write_b128 ----
#pragma unroll
        for (int r4 = 0; r4 < 4; ++r4) {
            const int row = trow + (r4 << 5);
            float av[8] = { aP[r4*2].x,   aP[r4*2].y,   aP[r4*2].z,   aP[r4*2].w,
                            aP[r4*2+1].x, aP[r4*2+1].y, aP[r4*2+1].z, aP[r4*2+1].w };
            if (MIX) {
                const float pr[8] = { pP[r4*2].x,   pP[r4*2].y,   pP[r4*2].z,   pP[r4*2].w,
                                      pP[r4*2+1].x, pP[r4*2+1].y, pP[r4*2+1].z, pP[r4*2+1].w };
#pragma unroll
                for (int e = 0; e < 8; ++e) av[e] = pr[e] + mxv[e] * (av[e] - pr[e]);
            }
            const unsigned off = ((unsigned)row << 6) + (unsigned)tcol;
            const unsigned swz = off ^ (((unsigned)(row & 7)) << 3);
            bf16x8 hv, lv;
#pragma unroll
            for (int e = 0; e < 8; ++e) {
                const __bf16 h = (__bf16)av[e];
                hv[e] = h;
                lv[e] = (__bf16)(av[e] - (float)h);
            }
            *(bf16x8*)&Ah[swz] = hv;
            *(bf16x8*)&Al[swz] = lv;

            const float wv[8] = { wP[r4*2].x,   wP[r4*2].y,   wP[r4*2].z,   wP[r4*2].w,
                                  wP[r4*2+1].x, wP[r4*2+1].y, wP[r4*2+1].z, wP[r4*2+1].w };
#pragma unroll
            for (int e = 0; e < 8; ++e) {
                const __bf16 h = (__bf16)wv[e];
                hv[e] = h;
                lv[e] = (__bf16)(wv[e] - (float)h);
            }
            *(bf16x8*)&Bh[swz] = hv;
            *(bf16x8*)&Bl[swz] = lv;
        }
        if (kt + 64 < K) issue(kt + 64);    // prefetch stays in flight across barrier
        barrier_before_read();
        // ---- MFMA: acc += Ah*Bh + Ah*Bl + Al*Bh (grouped: dep distance 4) ----
#pragma unroll
        for (int kk = 0; kk < 2; ++kk) {
            bf16x8 ah[4], al[4], bh[4], bl[4];
#pragma unroll
            for (int i = 0; i < 4; ++i) {
                const int ar = wm + (i << 4) + lr;
                const unsigned ao = (((unsigned)ar << 6) + (kk << 5) + (ls << 3))
                                    ^ (((unsigned)(ar & 7)) << 3);
                ah[i] = *(const bf16x8*)&Ah[ao];
                al[i] = *(const bf16x8*)&Al[ao];
                const int br = wn + (i << 4) + lr;
                const unsigned bo = (((unsigned)br << 6) + (kk << 5) + (ls << 3))
                                    ^ (((unsigned)(br & 7)) << 3);
                bh[i] = *(const bf16x8*)&Bh[bo];
                bl[i] = *(const bf16x8*)&Bl[bo];
            }
            __builtin_amdgcn_s_setprio(1);
#pragma unroll
            for (int i = 0; i < 4; ++i) {
#pragma unroll
                for (int j = 0; j < 4; ++j)
                    acc[i][j] = __builtin_amdgcn_mfma_f32_16x16x32_bf16(ah[i], bh[j], acc[i][j], 0, 0, 0);
#pragma unroll
                for (int j = 0; j < 4; ++j)
                    acc[i][j] = __builtin_amdgcn_mfma_f32_16x16x32_bf16(ah[i], bl[j], acc[i][j], 0, 0, 0);
#pragma unroll
                for (int j = 0; j < 4; ++j)
                    acc[i][j] = __builtin_amdgcn_mfma_f32_16x16x32_bf16(al[i], bh[j], acc[i][j], 0, 0, 0);
            }
            __builtin_amdgcn_s_setprio(0);
        }
        barrier_after_read();
    }
    // ---- epilogue (C/D layout: col = lane&15, row = (lane>>4)*4 + reg) ----
#pragma unroll
    for (int i = 0; i < 4; ++i) {
        const int gr0 = oRowOff + m0 + wm + (i << 4) + (ls << 2);
#pragma unroll
        for (int j = 0; j < 4; ++j) {
            const int gc = n0 + wn + (j << 4) + lr;
#pragma unroll
            for (int q = 0; q < 4; ++q) {
                const size_t o = (size_t)(gr0 + q) * N + gc;
                float val = acc[i][j][q];
                if constexpr (EPI == 1) {
                    val += X1[o];
                } else if constexpr (EPI == 2) {
                    val = fmaxf(val, 0.f); val *= val;
                } else if constexpr (EPI == 3) {
                    const float s = __fdividef(1.f, 1.f + __expf(-val));
                    val = X1[o] + s * X2[o];
                }
                out[o] = val;
            }
        }
    }
}

// ---------------------------------------------------------------------------
extern "C" void kernel_launch(void* const* d_in, const int* in_sizes, int n_in,
                              void* d_out, int out_size, void* d_ws, size_t ws_size,
                              hipStream_t stream)
{
    (void)in_sizes; (void)n_in; (void)out_size; (void)ws_size;
    const float* x   = (const float*)d_in[0];
    const float* sha = (const float*)d_in[1];
    const float* shf = (const float*)d_in[2];
    const float* wst = (const float*)d_in[3];
    const float* l1g = (const float*)d_in[4];
    const float* l1b = (const float*)d_in[5];
    const float* l2g = (const float*)d_in[6];
    const float* l2b = (const float*)d_in[7];
    const float* tmk = (const float*)d_in[8];
    const float* tmv = (const float*)d_in[9];
    const float* tmr = (const float*)d_in[10];
    const float* td  = (const float*)d_in[11];
    const float* tf  = (const float*)d_in[12];
    const float* Wk  = (const float*)d_in[13];
    const float* Wv  = (const float*)d_in[14];
    const float* Wr  = (const float*)d_in[15];
    const float* Wo  = (const float*)d_in[16];
    const float* fmk = (const float*)d_in[17];
    const float* fmr = (const float*)d_in[18];
    const float* Wkf = (const float*)d_in[19];
    const float* Wvf = (const float*)d_in[20];
    const float* Wrf = (const float*)d_in[21];

    float* xa = (float*)d_ws;           // [B*T, C]  xa; later reused as kf chunk
    float* bK = xa + BTC;               // k; later x1
    float* bV = bK + BTC;               // v; later xf
    float* bR = bV + BTC;               // r -> sr*y; later kv

    float* o_x  = (float*)d_out;                 // x out        [B,T,C]
    float* o_xa = o_x + BTC;                     // xa[:, -1]    [B,C]
    float* o_xf = o_xa + (size_t)BB * CC;        // xf[:, -1]    [B,C]
    float* o_st = o_xf + (size_t)BB * CC;        // new_wkv      [B,C,3]

    const int M = BB * TT;                       // 16384
    const int gCC = (M / 128) * (CC / 128);      // 2048 blocks
    dim3 blk(256);

    // ---- attention (time-mix) ----
    ln_kernel<<<M, blk, 0, stream>>>(x, l1g, l1b, xa, o_xa);
    gemm_kernel<0, true, 3><<<gCC * 3, blk, 0, stream>>>(
        xa, Wk, Wv, Wr, tmk, tmv, tmr, sha, nullptr, nullptr, bK, bV, bR, CC, CC, 0, 0);
    wkv_kernel<<<BB * CC / 64, dim3(64), 0, stream>>>(bK, bV, bR, td, tf, wst, bR, o_st);
    gemm_kernel<1, false, 1><<<gCC, blk, 0, stream>>>(
        bR, Wo, nullptr, nullptr, nullptr, nullptr, nullptr, nullptr, x, nullptr,
        bK, nullptr, nullptr, CC, CC, 0, 0);

    // ---- FFN (channel-mix) ----
    ln_kernel<<<M, blk, 0, stream>>>(bK, l2g, l2b, bV, o_xf);
    for (int ch = 0; ch < 4; ++ch) {             // 4096-row chunks
        gemm_kernel<2, true, 1><<<(4096 / 128) * (FF / 128), blk, 0, stream>>>(
            bV, Wkf, nullptr, nullptr, fmk, nullptr, nullptr, shf, nullptr, nullptr,
            xa, nullptr, nullptr, FF, CC, ch * 4096, 0);
        gemm_kernel<0, false, 1><<<(4096 / 128) * (CC / 128), blk, 0, stream>>>(
            xa, Wvf, nullptr, nullptr, nullptr, nullptr, nullptr, nullptr, nullptr, nullptr,
            bR, nullptr, nullptr, CC, FF, 0, ch * 4096);
    }
    gemm_kernel<3, true, 1><<<gCC, blk, 0, stream>>>(
        bV, Wrf, nullptr, nullptr, fmr, nullptr, nullptr, shf, bK, bR,
        o_x, nullptr, nullptr, CC, CC, 0, 0);
}